// Round 7
// baseline (710.802 us; speedup 1.0000x reference)
//
#include <hip/hip_runtime.h>
#include <hip/hip_bf16.h>
#include <stdint.h>

#define L_SEQ 4096
#define H_DIM 768
#define N_HEADS 12
#define D_HEAD 64
#define N_CHUNK 32
#define CHUNK 128
#define FF_DIM 3072
#define OUT_DIM 384
#define BATCH 2
#define EPS_LN 1e-5f
#define M_ROWS (BATCH * L_SEQ)   /* 8192 */
#define QKV_LD (3 * H_DIM)       /* 2304 */
#define NSEG 16                   /* global-row segments: 4096/256 */

typedef unsigned short u16;
typedef __bf16 bx8 __attribute__((ext_vector_type(8)));
typedef float fx4 __attribute__((ext_vector_type(4)));
typedef u16 ux8 __attribute__((ext_vector_type(8)));

__device__ __forceinline__ u16 f2bf(float f) {
  union { float f; unsigned u; } x; x.f = f;
  unsigned r = x.u + 0x7fffu + ((x.u >> 16) & 1u);
  return (u16)(r >> 16);
}
__device__ __forceinline__ float bf2f(u16 v) {
  union { unsigned u; float f; } x; x.u = ((unsigned)v) << 16;
  return x.f;
}

__device__ __forceinline__ void gload16(const void* g, void* l) {
  __builtin_amdgcn_global_load_lds((const __attribute__((address_space(1))) void*)g,
                                   (__attribute__((address_space(3))) void*)l, 16, 0, 0);
}

// =====================================================================
// Wide TLP GEMM: 128x256 tile, BK=64, 8 waves (2x4, per-wave 64x64),
// single-buffered 48 KiB LDS, 2 barriers per K-step, 2 blocks/CU.
// 6 gload_lds per thread per K-step for 256 MFMA/block-step (vs 8:128
// in the 128x128 variant) -- 2.7x better load:compute ratio; latency
// hiding from inter-block TLP (rounds 3-5 showed intra-block pipelining
// regresses here).
// LDS: As[128][64], Bs[256][64] u16; chunk c of row r at c ^ (r&7).
// Staging rows per lane differ by multiples of 8 -> row&7 == (lane>>3)&7
// for all, so one pre-swizzled source column serves all gloads; reads
// use the same XOR -> conflict-free (verified: r6 conflicts == 0).
// =====================================================================
template<int OUT_BF16, int DO_GELU>
__global__ __launch_bounds__(512, 4)
void gemm_w(const u16* __restrict__ A, const u16* __restrict__ Bt,
            const float* __restrict__ bias,
            float* __restrict__ Cf, u16* __restrict__ Cb,
            int N, int K)
{
  __shared__ __align__(16) u16 As[128 * 64];
  __shared__ __align__(16) u16 Bs[256 * 64];
  const int tid = threadIdx.x;
  const int lane = tid & 63, w = tid >> 6;
  const int c16 = lane & 15, g = lane >> 4;
  const int wm = w >> 2, wn = w & 3;

  const int nbn = N >> 8;
  int id = blockIdx.x;
  id = (id & 7) * (gridDim.x >> 3) + (id >> 3);   // XCD swizzle (grids %8==0)
  const int bm = id / nbn, bn = id % nbn;

  // staging: pre-swizzled source chunk; linear gload_lds dests
  const int schunk = (lane & 7) ^ ((lane >> 3) & 7);
  const u16* sA = A + (size_t)(bm * 128 + w * 16 + (lane >> 3)) * K + schunk * 8;
  const u16* sB = Bt + (size_t)(bn * 256 + w * 32 + (lane >> 3)) * K + schunk * 8;

  fx4 acc[4][4] = {};

  for (int k0 = 0; k0 < K; k0 += 64) {
    gload16(sA + k0, &As[w * 1024]);
    gload16(sA + (size_t)8 * K + k0, &As[w * 1024 + 512]);
    #pragma unroll
    for (int i = 0; i < 4; i++)
      gload16(sB + (size_t)(i * 8) * K + k0, &Bs[w * 2048 + i * 512]);
    __syncthreads();   // vmcnt(0) drain; hidden by the other block on this CU
    #pragma unroll
    for (int h = 0; h < 2; h++) {
      bx8 af[4], bf[4];
      #pragma unroll
      for (int m = 0; m < 4; m++) {
        const int row = wm * 64 + m * 16 + c16;
        af[m] = *(const bx8*)&As[row * 64 + (((h << 2) + g) ^ (c16 & 7)) * 8];
      }
      #pragma unroll
      for (int n = 0; n < 4; n++) {
        const int row = wn * 64 + n * 16 + c16;
        bf[n] = *(const bx8*)&Bs[row * 64 + (((h << 2) + g) ^ (c16 & 7)) * 8];
      }
      #pragma unroll
      for (int m = 0; m < 4; m++)
        #pragma unroll
        for (int n = 0; n < 4; n++)
          acc[m][n] = __builtin_amdgcn_mfma_f32_16x16x32_bf16(af[m], bf[n], acc[m][n], 0, 0, 0);
    }
    __syncthreads();
  }

  const int row0 = bm * 128 + wm * 64 + g * 4;
  const int col0 = bn * 256 + wn * 64 + c16;
  #pragma unroll
  for (int n = 0; n < 4; n++) {
    const int col = col0 + n * 16;
    const float bb = bias[col];
    #pragma unroll
    for (int m = 0; m < 4; m++) {
      #pragma unroll
      for (int r = 0; r < 4; r++) {
        float y = acc[m][n][r] + bb;
        if (DO_GELU) {
          const float tt = y;
          y = 0.5f * tt * (1.0f + tanhf(0.7978845608f * (tt + 0.044715f * tt * tt * tt)));
        }
        const size_t idx = (size_t)(row0 + m * 16 + r) * N + col;
        if (OUT_BF16) Cb[idx] = f2bf(y);
        else Cf[idx] = y;
      }
    }
  }
}

// ---------------- 128x128 TLP GEMM (r6, kept for N=384 final) ----------------
template<int OUT_BF16, int DO_GELU>
__global__ __launch_bounds__(256, 3)
void gemm_s(const u16* __restrict__ A, const u16* __restrict__ Bt,
            const float* __restrict__ bias,
            float* __restrict__ Cf, u16* __restrict__ Cb,
            int N, int K)
{
  __shared__ __align__(16) u16 As[128 * 64];
  __shared__ __align__(16) u16 Bs[128 * 64];
  const int tid = threadIdx.x;
  const int lane = tid & 63, w = tid >> 6;
  const int c16 = lane & 15, g = lane >> 4;
  const int wr = w >> 1, wc = w & 1;

  const int nbn = N >> 7;
  int id = blockIdx.x;
  id = (id & 7) * (gridDim.x >> 3) + (id >> 3);
  const int bm = id / nbn, bn = id % nbn;

  const int srow = w * 8 + (lane >> 3);
  const int schunk = (lane & 7) ^ (lane >> 3);
  const u16* sA = A + (size_t)(bm * 128 + srow) * K + schunk * 8;
  const u16* sB = Bt + (size_t)(bn * 128 + srow) * K + schunk * 8;
  const int wdst = w * 512;

  fx4 acc[4][4] = {};

  for (int k0 = 0; k0 < K; k0 += 64) {
    #pragma unroll
    for (int i = 0; i < 4; i++) {
      gload16(sA + (size_t)(i * 32) * K + k0, &As[i * 2048 + wdst]);
      gload16(sB + (size_t)(i * 32) * K + k0, &Bs[i * 2048 + wdst]);
    }
    __syncthreads();
    #pragma unroll
    for (int h = 0; h < 2; h++) {
      bx8 af[4], bf[4];
      #pragma unroll
      for (int m = 0; m < 4; m++) {
        const int row = wr * 64 + m * 16 + c16;
        af[m] = *(const bx8*)&As[row * 64 + (((h << 2) + g) ^ (c16 & 7)) * 8];
      }
      #pragma unroll
      for (int n = 0; n < 4; n++) {
        const int row = wc * 64 + n * 16 + c16;
        bf[n] = *(const bx8*)&Bs[row * 64 + (((h << 2) + g) ^ (c16 & 7)) * 8];
      }
      #pragma unroll
      for (int m = 0; m < 4; m++)
        #pragma unroll
        for (int n = 0; n < 4; n++)
          acc[m][n] = __builtin_amdgcn_mfma_f32_16x16x32_bf16(af[m], bf[n], acc[m][n], 0, 0, 0);
    }
    __syncthreads();
  }

  const int row0 = bm * 128 + wr * 64 + g * 4;
  const int col0 = bn * 128 + wc * 64 + c16;
  #pragma unroll
  for (int n = 0; n < 4; n++) {
    const int col = col0 + n * 16;
    const float bb = bias[col];
    #pragma unroll
    for (int m = 0; m < 4; m++) {
      #pragma unroll
      for (int r = 0; r < 4; r++) {
        float y = acc[m][n][r] + bb;
        if (DO_GELU) {
          const float tt = y;
          y = 0.5f * tt * (1.0f + tanhf(0.7978845608f * (tt + 0.044715f * tt * tt * tt)));
        }
        const size_t idx = (size_t)(row0 + m * 16 + r) * N + col;
        if (OUT_BF16) Cb[idx] = f2bf(y);
        else Cf[idx] = y;
      }
    }
  }
}

// ---------------- Local (windowed) attention ----------------
#define V_STR 424

__global__ __launch_bounds__(512, 2)
void attn_local_kernel(const u16* __restrict__ qkv, const int* __restrict__ amask,
                       u16* __restrict__ attnout)
{
  __shared__ __align__(16) u16 Vlds[64 * V_STR];        // V^T: [d][key]
  __shared__ __align__(16) u16 Plds[8 * 16 * V_STR];    // per-wave P: [q][key]

  const int tid = threadIdx.x;
  const int lane = tid & 63, w = tid >> 6;
  const int c16 = lane & 15, g = lane >> 4;

  const int bh = blockIdx.x >> 5;
  const int n = blockIdx.x & 31;
  const int b = bh / N_HEADS, h = bh % N_HEADS;

  const u16* qkvb = qkv + (size_t)b * L_SEQ * QKV_LD + h * D_HEAD;
  const int chunk_lo = n * CHUNK - CHUNK;

  for (int idx = tid; idx < 416 * 8; idx += 512) {
    const int j = idx >> 3, d8 = (idx & 7) * 8;
    if (j >= 385) {
      #pragma unroll
      for (int i = 0; i < 8; i++) Vlds[(d8 + i) * V_STR + j] = 0;
    } else {
      int pos = (j == 384) ? 0 : chunk_lo + j;
      if (pos < 0 || pos >= L_SEQ) pos = 0;
      ux8 vv = *(const ux8*)(qkvb + (size_t)pos * QKV_LD + 2 * H_DIM + d8);
      #pragma unroll
      for (int i = 0; i < 8; i++) Vlds[(d8 + i) * V_STR + j] = vv[i];
    }
  }

  const int qrow = n * CHUNK + w * 16 + c16;
  const u16* qp = qkvb + (size_t)qrow * QKV_LD + g * 8;
  const bx8 aq0 = *(const bx8*)qp;
  const bx8 aq1 = *(const bx8*)(qp + 32);

  unsigned kvm = 0;
  #pragma unroll
  for (int kf = 0; kf < 24; kf++) {
    const int pos = chunk_lo + kf * 16 + c16;
    bool ok = (pos >= 1) && (pos < L_SEQ);
    if (ok) ok = (amask[b * L_SEQ + pos] > 0);
    kvm |= ((unsigned)ok) << kf;
  }

  fx4 s[26];
  #pragma unroll
  for (int kf = 0; kf < 25; kf++) {
    int pos = (kf == 24) ? 0 : chunk_lo + kf * 16 + c16;
    if (pos < 0 || pos >= L_SEQ) pos = 0;
    const u16* kp = qkvb + (size_t)pos * QKV_LD + H_DIM + g * 8;
    const bx8 b0 = *(const bx8*)kp;
    const bx8 b1 = *(const bx8*)(kp + 32);
    fx4 a = {};
    a = __builtin_amdgcn_mfma_f32_16x16x32_bf16(aq0, b0, a, 0, 0, 0);
    a = __builtin_amdgcn_mfma_f32_16x16x32_bf16(aq1, b1, a, 0, 0, 0);
    s[kf] = a;
  }

  const int cq = w * 16 + g * 4;
  float mx[4], sm[4];
  #pragma unroll
  for (int r = 0; r < 4; r++) mx[r] = -3.0e38f;
  #pragma unroll
  for (int kf = 0; kf < 25; kf++) {
    const int j = kf * 16 + c16;
    const bool kv = (kf < 24) ? (((kvm >> kf) & 1u) != 0) : (c16 == 0);
    #pragma unroll
    for (int r = 0; r < 4; r++) {
      const int c = cq + r;
      const bool keep = kv && (kf == 24 || (j >= c && j <= c + 256));
      const float val = keep ? s[kf][r] * 0.125f : -1.0e9f;
      s[kf][r] = val;
      mx[r] = fmaxf(mx[r], val);
    }
  }
  #pragma unroll
  for (int r = 0; r < 4; r++) {
    float m = mx[r];
    m = fmaxf(m, __shfl_xor(m, 1));
    m = fmaxf(m, __shfl_xor(m, 2));
    m = fmaxf(m, __shfl_xor(m, 4));
    m = fmaxf(m, __shfl_xor(m, 8));
    mx[r] = m;
    sm[r] = 0.f;
  }
  #pragma unroll
  for (int kf = 0; kf < 25; kf++)
    #pragma unroll
    for (int r = 0; r < 4; r++) {
      const float p = __expf(s[kf][r] - mx[r]);
      s[kf][r] = p;
      sm[r] += p;
    }
  float rinv[4];
  #pragma unroll
  for (int r = 0; r < 4; r++) {
    float t = sm[r];
    t += __shfl_xor(t, 1);
    t += __shfl_xor(t, 2);
    t += __shfl_xor(t, 4);
    t += __shfl_xor(t, 8);
    rinv[r] = 1.0f / t;
  }
  s[25] = (fx4){0.f, 0.f, 0.f, 0.f};

  u16* pb = Plds + (size_t)w * 16 * V_STR;
  #pragma unroll
  for (int kf = 0; kf < 26; kf++) {
    const int j = kf * 16 + c16;
    #pragma unroll
    for (int r = 0; r < 4; r++)
      pb[(g * 4 + r) * V_STR + j] = f2bf(s[kf][r]);
  }
  __syncthreads();

  fx4 o[4] = {};
  const u16* pr = Plds + (size_t)(w * 16 + c16) * V_STR + g * 8;
  #pragma unroll
  for (int kt = 0; kt < 13; kt++) {
    const bx8 pa = *(const bx8*)(pr + kt * 32);
    #pragma unroll
    for (int df = 0; df < 4; df++) {
      const bx8 vvf = *(const bx8*)&Vlds[(df * 16 + c16) * V_STR + kt * 32 + g * 8];
      o[df] = __builtin_amdgcn_mfma_f32_16x16x32_bf16(pa, vvf, o[df], 0, 0, 0);
    }
  }

  u16* ob = attnout + (size_t)b * L_SEQ * H_DIM + h * D_HEAD;
  const int posq = n * CHUNK + w * 16 + g * 4;
  #pragma unroll
  for (int df = 0; df < 4; df++)
    #pragma unroll
    for (int r = 0; r < 4; r++)
      ob[(size_t)(posq + r) * H_DIM + df * 16 + c16] = f2bf(o[df][r] * rinv[r]);
}

// ---------------- Global row (query position 0) ----------------
__global__ __launch_bounds__(256)
void attn_g_score(const u16* __restrict__ qkv, const int* __restrict__ amask,
                  float* __restrict__ sbuf, float* __restrict__ pmax)
{
  __shared__ float qs[D_HEAD];
  __shared__ float red[4];
  const int seg = blockIdx.x, bh = blockIdx.y;
  const int b = bh / N_HEADS, h = bh % N_HEADS;
  const u16* base = qkv + (size_t)b * L_SEQ * QKV_LD + h * D_HEAD;
  const int tid = threadIdx.x;

  if (tid < D_HEAD) qs[tid] = bf2f(base[tid]);
  __syncthreads();

  const int l = seg * 256 + tid;
  const ux8* kp = (const ux8*)(base + (size_t)l * QKV_LD + H_DIM);
  float dot = 0.f;
  #pragma unroll
  for (int i = 0; i < 8; i++) {
    const ux8 kv = kp[i];
    #pragma unroll
    for (int j = 0; j < 8; j++) dot += qs[i * 8 + j] * bf2f(kv[j]);
  }
  float sv = dot * 0.125f;
  if (amask[b * L_SEQ + l] == 0) sv = -1.0e9f;
  sbuf[(size_t)bh * L_SEQ + l] = sv;

  float m = sv;
  #pragma unroll
  for (int off = 32; off > 0; off >>= 1) m = fmaxf(m, __shfl_xor(m, off));
  if ((tid & 63) == 0) red[tid >> 6] = m;
  __syncthreads();
  if (tid == 0)
    pmax[bh * NSEG + seg] = fmaxf(fmaxf(red[0], red[1]), fmaxf(red[2], red[3]));
}

__global__ __launch_bounds__(256)
void attn_g_pv(const u16* __restrict__ qkv, const float* __restrict__ sbuf,
               const float* __restrict__ pmax, float* __restrict__ psum,
               float* __restrict__ po)
{
  __shared__ float es[256];
  __shared__ float red[4];
  const int seg = blockIdx.x, bh = blockIdx.y;
  const int b = bh / N_HEADS, h = bh % N_HEADS;
  const int tid = threadIdx.x;

  float M = -3.0e38f;
  #pragma unroll
  for (int i = 0; i < NSEG; i++) M = fmaxf(M, pmax[bh * NSEG + i]);

  const int l = seg * 256 + tid;
  const float e = __expf(sbuf[(size_t)bh * L_SEQ + l] - M);
  es[tid] = e;

  float t = e;
  #pragma unroll
  for (int off = 32; off > 0; off >>= 1) t += __shfl_xor(t, off);
  if ((tid & 63) == 0) red[tid >> 6] = t;
  __syncthreads();
  if (tid == 0) psum[bh * NSEG + seg] = red[0] + red[1] + red[2] + red[3];

  const int d = tid & 63, grp = tid >> 6;
  const u16* vb = qkv + (size_t)b * L_SEQ * QKV_LD + h * D_HEAD + 2 * H_DIM + d;
  float acc = 0.f;
  #pragma unroll 4
  for (int i = 0; i < 64; i++) {
    const int ll = seg * 256 + grp * 64 + i;
    acc += es[grp * 64 + i] * bf2f(vb[(size_t)ll * QKV_LD]);
  }
  po[(((size_t)bh * NSEG + seg) * 4 + grp) * D_HEAD + d] = acc;
}

__global__ __launch_bounds__(64)
void attn_g_combine(const float* __restrict__ psum, const float* __restrict__ po,
                    u16* __restrict__ attnout)
{
  const int bh = blockIdx.x;
  const int b = bh / N_HEADS, h = bh % N_HEADS;
  const int d = threadIdx.x;
  float S = 0.f;
  #pragma unroll
  for (int i = 0; i < NSEG; i++) S += psum[bh * NSEG + i];
  float acc = 0.f;
  #pragma unroll
  for (int i = 0; i < NSEG * 4; i++)
    acc += po[((size_t)bh * NSEG * 4 + i) * D_HEAD + d];
  attnout[(size_t)b * L_SEQ * H_DIM + h * D_HEAD + d] = f2bf(acc / S);
}

// ---------------- LayerNorm kernels ----------------
__device__ __forceinline__ void block_stats(float sum, float sq, float* red,
                                            float& mean, float& rstd)
{
  const int lane = threadIdx.x & 63, wv = threadIdx.x >> 6;
  #pragma unroll
  for (int off = 32; off > 0; off >>= 1) {
    sum += __shfl_xor(sum, off);
    sq  += __shfl_xor(sq, off);
  }
  if (lane == 0) { red[wv] = sum; red[4 + wv] = sq; }
  __syncthreads();
  sum = red[0] + red[1] + red[2] + red[3];
  sq  = red[4] + red[5] + red[6] + red[7];
  mean = sum * (1.0f / H_DIM);
  const float var = sq * (1.0f / H_DIM) - mean * mean;
  rstd = rsqrtf(var + EPS_LN);
}

__global__ __launch_bounds__(256)
void embed_ln_kernel(const int* __restrict__ ids, const float* __restrict__ wemb,
                     const float* __restrict__ pemb, const float* __restrict__ gam,
                     const float* __restrict__ bet, float* __restrict__ xf,
                     u16* __restrict__ xb)
{
  __shared__ float red[8];
  const int row = blockIdx.x, tid = threadIdx.x;
  const int l = row & (L_SEQ - 1);
  const int id = ids[row];
  float v[3]; float sum = 0.f, sq = 0.f;
  #pragma unroll
  for (int i = 0; i < 3; i++) {
    const int c = tid + i * 256;
    const float t = wemb[(size_t)id * H_DIM + c] + pemb[(size_t)l * H_DIM + c];
    v[i] = t; sum += t; sq += t * t;
  }
  float mean, rstd;
  block_stats(sum, sq, red, mean, rstd);
  #pragma unroll
  for (int i = 0; i < 3; i++) {
    const int c = tid + i * 256;
    const float y = (v[i] - mean) * rstd * gam[c] + bet[c];
    xf[(size_t)row * H_DIM + c] = y;
    xb[(size_t)row * H_DIM + c] = f2bf(y);
  }
}

__global__ __launch_bounds__(256)
void add_ln_kernel(float* xio, const u16* __restrict__ yin,
                   const float* __restrict__ gam, const float* __restrict__ bet,
                   u16* __restrict__ xb)
{
  __shared__ float red[8];
  const int row = blockIdx.x, tid = threadIdx.x;
  float v[3]; float sum = 0.f, sq = 0.f;
  #pragma unroll
  for (int i = 0; i < 3; i++) {
    const int c = tid + i * 256;
    const float t = xio[(size_t)row * H_DIM + c] + bf2f(yin[(size_t)row * H_DIM + c]);
    v[i] = t; sum += t; sq += t * t;
  }
  float mean, rstd;
  block_stats(sum, sq, red, mean, rstd);
  #pragma unroll
  for (int i = 0; i < 3; i++) {
    const int c = tid + i * 256;
    const float y = (v[i] - mean) * rstd * gam[c] + bet[c];
    xio[(size_t)row * H_DIM + c] = y;
    xb[(size_t)row * H_DIM + c] = f2bf(y);
  }
}

// ---------------- weight transpose fp32 -> bf16 ----------------
__global__ __launch_bounds__(256)
void transpose_w_kernel(const float* __restrict__ W, u16* __restrict__ Wt, int K, int N)
{
  __shared__ float tile[32][33];
  const int k0 = blockIdx.x * 32, n0 = blockIdx.y * 32;
  const int tx = threadIdx.x & 31, ty = threadIdx.x >> 5;
  #pragma unroll
  for (int i = 0; i < 32; i += 8)
    tile[ty + i][tx] = W[(size_t)(k0 + ty + i) * N + n0 + tx];
  __syncthreads();
  #pragma unroll
  for (int i = 0; i < 32; i += 8)
    Wt[(size_t)(n0 + ty + i) * K + k0 + tx] = f2bf(tile[tx][ty + i]);
}

__global__ void concat3_kernel(const float* __restrict__ a, const float* __restrict__ b,
                               const float* __restrict__ c, float* __restrict__ out)
{
  const int i = blockIdx.x * 256 + threadIdx.x;
  if (i < H_DIM) out[i] = a[i];
  else if (i < 2 * H_DIM) out[i] = b[i - H_DIM];
  else if (i < 3 * H_DIM) out[i] = c[i - 2 * H_DIM];
}

__global__ void cls_copy_kernel(const float* __restrict__ vdn, float* __restrict__ cls)
{
  const int i = blockIdx.x * 256 + threadIdx.x;
  if (i < BATCH * OUT_DIM)
    cls[i] = vdn[(size_t)(i / OUT_DIM) * L_SEQ * OUT_DIM + (i % OUT_DIM)];
}

// ---------------- host ----------------
extern "C" void kernel_launch(void* const* d_in, const int* in_sizes, int n_in,
                              void* d_out, int out_size, void* d_ws, size_t ws_size,
                              hipStream_t stream)
{
  (void)in_sizes; (void)n_in; (void)out_size; (void)ws_size;
  const int*   ids   = (const int*)d_in[0];
  const int*   amask = (const int*)d_in[1];
  const float* wemb  = (const float*)d_in[2];
  const float* pemb  = (const float*)d_in[3];
  const float* elns  = (const float*)d_in[4];
  const float* elnb  = (const float*)d_in[5];
  const float* Wq    = (const float*)d_in[6];
  const float* bq    = (const float*)d_in[7];
  const float* Wk    = (const float*)d_in[8];
  const float* bk    = (const float*)d_in[9];
  const float* Wv    = (const float*)d_in[10];
  const float* bv    = (const float*)d_in[11];
  const float* Wo    = (const float*)d_in[12];
  const float* bo    = (const float*)d_in[13];
  const float* ln1s  = (const float*)d_in[14];
  const float* ln1b  = (const float*)d_in[15];
  const float* W1    = (const float*)d_in[16];
  const float* b1    = (const float*)d_in[17];
  const float* W2    = (const float*)d_in[18];
  const float* b2    = (const float*)d_in[19];
  const float* ln2s  = (const float*)d_in[20];
  const float* ln2b  = (const float*)d_in[21];
  const float* Wfc   = (const float*)d_in[22];
  const float* bfc   = (const float*)d_in[23];

  char* ws = (char*)d_ws;
  size_t off = 0;
  auto alloc = [&](size_t bytes) -> void* {
    void* p = ws + off;
    off += (bytes + 255) & ~(size_t)255;
    return p;
  };
  float* xf   = (float*)alloc((size_t)M_ROWS * H_DIM * 4);
  u16* projb  = (u16*)alloc((size_t)M_ROWS * H_DIM * 2);
  u16* xb     = (u16*)alloc((size_t)M_ROWS * H_DIM * 2);
  u16* big    = (u16*)alloc((size_t)M_ROWS * FF_DIM * 2);  // qkv / ff1 time-share
  u16* attno  = (u16*)alloc((size_t)M_ROWS * H_DIM * 2);
  u16* wqkvT  = (u16*)alloc((size_t)QKV_LD * H_DIM * 2);
  u16* woT    = (u16*)alloc((size_t)H_DIM * H_DIM * 2);
  u16* w1T    = (u16*)alloc((size_t)FF_DIM * H_DIM * 2);
  u16* w2T    = (u16*)alloc((size_t)H_DIM * FF_DIM * 2);
  u16* wfcT   = (u16*)alloc((size_t)OUT_DIM * H_DIM * 2);
  float* bqkv = (float*)alloc(QKV_LD * 4);
  float* gsc  = (float*)alloc((size_t)BATCH * N_HEADS * L_SEQ * 4);
  float* gpm  = (float*)alloc((size_t)BATCH * N_HEADS * NSEG * 4);
  float* gps  = (float*)alloc((size_t)BATCH * N_HEADS * NSEG * 4);
  float* gpo  = (float*)alloc((size_t)BATCH * N_HEADS * NSEG * 4 * D_HEAD * 4);

  u16* qkvb = big;
  u16* ff1  = big;

  embed_ln_kernel<<<M_ROWS, 256, 0, stream>>>(ids, wemb, pemb, elns, elnb, xf, xb);

  for (int l = 0; l < 2; l++) {
    const size_t wof = (size_t)l * H_DIM * H_DIM;
    transpose_w_kernel<<<dim3(24, 24), 256, 0, stream>>>(Wq + wof, wqkvT, H_DIM, H_DIM);
    transpose_w_kernel<<<dim3(24, 24), 256, 0, stream>>>(Wk + wof, wqkvT + (size_t)H_DIM * H_DIM, H_DIM, H_DIM);
    transpose_w_kernel<<<dim3(24, 24), 256, 0, stream>>>(Wv + wof, wqkvT + (size_t)2 * H_DIM * H_DIM, H_DIM, H_DIM);
    transpose_w_kernel<<<dim3(24, 24), 256, 0, stream>>>(Wo + wof, woT, H_DIM, H_DIM);
    transpose_w_kernel<<<dim3(24, 96), 256, 0, stream>>>(W1 + (size_t)l * H_DIM * FF_DIM, w1T, H_DIM, FF_DIM);
    transpose_w_kernel<<<dim3(96, 24), 256, 0, stream>>>(W2 + (size_t)l * FF_DIM * H_DIM, w2T, FF_DIM, H_DIM);
    concat3_kernel<<<9, 256, 0, stream>>>(bq + l * H_DIM, bk + l * H_DIM, bv + l * H_DIM, bqkv);

    gemm_w<1, 0><<<(M_ROWS / 128) * (QKV_LD / 256), 512, 0, stream>>>(
        xb, wqkvT, bqkv, nullptr, qkvb, QKV_LD, H_DIM);
    attn_local_kernel<<<BATCH * N_HEADS * N_CHUNK, 512, 0, stream>>>(qkvb, amask, attno);
    attn_g_score<<<dim3(NSEG, BATCH * N_HEADS), 256, 0, stream>>>(qkvb, amask, gsc, gpm);
    attn_g_pv<<<dim3(NSEG, BATCH * N_HEADS), 256, 0, stream>>>(qkvb, gsc, gpm, gps, gpo);
    attn_g_combine<<<BATCH * N_HEADS, 64, 0, stream>>>(gps, gpo, attno);
    gemm_w<1, 0><<<(M_ROWS / 128) * (H_DIM / 256), 512, 0, stream>>>(
        attno, woT, bo + l * H_DIM, nullptr, projb, H_DIM, H_DIM);
    add_ln_kernel<<<M_ROWS, 256, 0, stream>>>(xf, projb, ln1s + l * H_DIM, ln1b + l * H_DIM, xb);
    gemm_w<1, 1><<<(M_ROWS / 128) * (FF_DIM / 256), 512, 0, stream>>>(
        xb, w1T, b1 + l * FF_DIM, nullptr, ff1, FF_DIM, H_DIM);
    gemm_w<1, 0><<<(M_ROWS / 128) * (H_DIM / 256), 512, 0, stream>>>(
        ff1, w2T, b2 + l * H_DIM, nullptr, projb, H_DIM, FF_DIM);
    add_ln_kernel<<<M_ROWS, 256, 0, stream>>>(xf, projb, ln2s + l * H_DIM, ln2b + l * H_DIM, xb);
  }

  transpose_w_kernel<<<dim3(24, 12), 256, 0, stream>>>(Wfc, wfcT, H_DIM, OUT_DIM);
  float* vdn = (float*)d_out;
  gemm_s<0, 0><<<(M_ROWS / 128) * (OUT_DIM / 128), 256, 0, stream>>>(
      xb, wfcT, bfc, vdn, nullptr, OUT_DIM, H_DIM);
  cls_copy_kernel<<<3, 256, 0, stream>>>(vdn, vdn + (size_t)BATCH * L_SEQ * OUT_DIM);
}

// Round 8
// 616.013 us; speedup vs baseline: 1.1539x; 1.1539x over previous
//
#include <hip/hip_runtime.h>
#include <hip/hip_bf16.h>
#include <stdint.h>

#define L_SEQ 4096
#define H_DIM 768
#define N_HEADS 12
#define D_HEAD 64
#define N_CHUNK 32
#define CHUNK 128
#define FF_DIM 3072
#define OUT_DIM 384
#define BATCH 2
#define EPS_LN 1e-5f
#define M_ROWS (BATCH * L_SEQ)   /* 8192 */
#define QKV_LD (3 * H_DIM)       /* 2304 */
#define NSEG 16                   /* global-row segments: 4096/256 */

typedef unsigned short u16;
typedef __bf16 bx8 __attribute__((ext_vector_type(8)));
typedef float fx4 __attribute__((ext_vector_type(4)));
typedef u16 ux8 __attribute__((ext_vector_type(8)));

__device__ __forceinline__ u16 f2bf(float f) {
  union { float f; unsigned u; } x; x.f = f;
  unsigned r = x.u + 0x7fffu + ((x.u >> 16) & 1u);
  return (u16)(r >> 16);
}
__device__ __forceinline__ float bf2f(u16 v) {
  union { unsigned u; float f; } x; x.u = ((unsigned)v) << 16;
  return x.f;
}

__device__ __forceinline__ void gload16(const void* g, void* l) {
  __builtin_amdgcn_global_load_lds((const __attribute__((address_space(1))) void*)g,
                                   (__attribute__((address_space(3))) void*)l, 16, 0, 0);
}

// =====================================================================
// TLP GEMM (r6-proven best): 128x128 tile, BK=64, 4 waves (2x2),
// single-buffered 32 KiB LDS, 2 barriers per K-step, 3 blocks/CU.
// Latency hiding from inter-block TLP — rounds 3-5 proved intra-block
// pipelining regresses here; round 7 proved grids must stay >= ~2.5x CUs.
// LDS: chunk c of row r at c ^ (r&7); pre-swizzled global source +
// swizzled read; conflicts == 0 (verified r6).
// DO_CLS: also write cls[b*OUT + col] for rows 0 / 4096 (final GEMM).
// =====================================================================
template<int OUT_BF16, int DO_GELU, int DO_CLS>
__global__ __launch_bounds__(256, 3)
void gemm_s(const u16* __restrict__ A, const u16* __restrict__ Bt,
            const float* __restrict__ bias,
            float* __restrict__ Cf, u16* __restrict__ Cb,
            float* __restrict__ cls,
            int N, int K)
{
  __shared__ __align__(16) u16 As[128 * 64];
  __shared__ __align__(16) u16 Bs[128 * 64];
  const int tid = threadIdx.x;
  const int lane = tid & 63, w = tid >> 6;
  const int c16 = lane & 15, g = lane >> 4;
  const int wr = w >> 1, wc = w & 1;

  const int nbn = N >> 7;
  int id = blockIdx.x;
  id = (id & 7) * (gridDim.x >> 3) + (id >> 3);   // XCD swizzle (grids %8==0)
  const int bm = id / nbn, bn = id % nbn;

  const int srow = w * 8 + (lane >> 3);
  const int schunk = (lane & 7) ^ (lane >> 3);
  const u16* sA = A + (size_t)(bm * 128 + srow) * K + schunk * 8;
  const u16* sB = Bt + (size_t)(bn * 128 + srow) * K + schunk * 8;
  const int wdst = w * 512;

  fx4 acc[4][4] = {};

  for (int k0 = 0; k0 < K; k0 += 64) {
    #pragma unroll
    for (int i = 0; i < 4; i++) {
      gload16(sA + (size_t)(i * 32) * K + k0, &As[i * 2048 + wdst]);
      gload16(sB + (size_t)(i * 32) * K + k0, &Bs[i * 2048 + wdst]);
    }
    __syncthreads();   // vmcnt(0) drain; hidden by other blocks on this CU
    #pragma unroll
    for (int h = 0; h < 2; h++) {
      bx8 af[4], bf[4];
      #pragma unroll
      for (int m = 0; m < 4; m++) {
        const int row = wr * 64 + m * 16 + c16;
        af[m] = *(const bx8*)&As[row * 64 + (((h << 2) + g) ^ (c16 & 7)) * 8];
      }
      #pragma unroll
      for (int n = 0; n < 4; n++) {
        const int row = wc * 64 + n * 16 + c16;
        bf[n] = *(const bx8*)&Bs[row * 64 + (((h << 2) + g) ^ (c16 & 7)) * 8];
      }
      #pragma unroll
      for (int m = 0; m < 4; m++)
        #pragma unroll
        for (int n = 0; n < 4; n++)
          acc[m][n] = __builtin_amdgcn_mfma_f32_16x16x32_bf16(af[m], bf[n], acc[m][n], 0, 0, 0);
    }
    __syncthreads();
  }

  const int row0 = bm * 128 + wr * 64 + g * 4;
  const int col0 = bn * 128 + wc * 64 + c16;
  #pragma unroll
  for (int n = 0; n < 4; n++) {
    const int col = col0 + n * 16;
    const float bb = bias[col];
    #pragma unroll
    for (int m = 0; m < 4; m++) {
      #pragma unroll
      for (int r = 0; r < 4; r++) {
        float y = acc[m][n][r] + bb;
        if (DO_GELU) {
          const float tt = y;
          y = 0.5f * tt * (1.0f + tanhf(0.7978845608f * (tt + 0.044715f * tt * tt * tt)));
        }
        const int row = row0 + m * 16 + r;
        const size_t idx = (size_t)row * N + col;
        if (OUT_BF16) Cb[idx] = f2bf(y);
        else Cf[idx] = y;
        if (DO_CLS) {
          if ((row & (L_SEQ - 1)) == 0)
            cls[(row >> 12) * OUT_DIM + col] = y;
        }
      }
    }
  }
}

// ---------------- Local (windowed) attention ----------------
#define V_STR 424

__global__ __launch_bounds__(512, 2)
void attn_local_kernel(const u16* __restrict__ qkv, const int* __restrict__ amask,
                       u16* __restrict__ attnout)
{
  __shared__ __align__(16) u16 Vlds[64 * V_STR];        // V^T: [d][key]
  __shared__ __align__(16) u16 Plds[8 * 16 * V_STR];    // per-wave P: [q][key]

  const int tid = threadIdx.x;
  const int lane = tid & 63, w = tid >> 6;
  const int c16 = lane & 15, g = lane >> 4;

  const int bh = blockIdx.x >> 5;
  const int n = blockIdx.x & 31;
  const int b = bh / N_HEADS, h = bh % N_HEADS;

  const u16* qkvb = qkv + (size_t)b * L_SEQ * QKV_LD + h * D_HEAD;
  const int chunk_lo = n * CHUNK - CHUNK;

  for (int idx = tid; idx < 416 * 8; idx += 512) {
    const int j = idx >> 3, d8 = (idx & 7) * 8;
    if (j >= 385) {
      #pragma unroll
      for (int i = 0; i < 8; i++) Vlds[(d8 + i) * V_STR + j] = 0;
    } else {
      int pos = (j == 384) ? 0 : chunk_lo + j;
      if (pos < 0 || pos >= L_SEQ) pos = 0;
      ux8 vv = *(const ux8*)(qkvb + (size_t)pos * QKV_LD + 2 * H_DIM + d8);
      #pragma unroll
      for (int i = 0; i < 8; i++) Vlds[(d8 + i) * V_STR + j] = vv[i];
    }
  }

  const int qrow = n * CHUNK + w * 16 + c16;
  const u16* qp = qkvb + (size_t)qrow * QKV_LD + g * 8;
  const bx8 aq0 = *(const bx8*)qp;
  const bx8 aq1 = *(const bx8*)(qp + 32);

  unsigned kvm = 0;
  #pragma unroll
  for (int kf = 0; kf < 24; kf++) {
    const int pos = chunk_lo + kf * 16 + c16;
    bool ok = (pos >= 1) && (pos < L_SEQ);
    if (ok) ok = (amask[b * L_SEQ + pos] > 0);
    kvm |= ((unsigned)ok) << kf;
  }

  fx4 s[26];
  #pragma unroll
  for (int kf = 0; kf < 25; kf++) {
    int pos = (kf == 24) ? 0 : chunk_lo + kf * 16 + c16;
    if (pos < 0 || pos >= L_SEQ) pos = 0;
    const u16* kp = qkvb + (size_t)pos * QKV_LD + H_DIM + g * 8;
    const bx8 b0 = *(const bx8*)kp;
    const bx8 b1 = *(const bx8*)(kp + 32);
    fx4 a = {};
    a = __builtin_amdgcn_mfma_f32_16x16x32_bf16(aq0, b0, a, 0, 0, 0);
    a = __builtin_amdgcn_mfma_f32_16x16x32_bf16(aq1, b1, a, 0, 0, 0);
    s[kf] = a;
  }

  const int cq = w * 16 + g * 4;
  float mx[4], sm[4];
  #pragma unroll
  for (int r = 0; r < 4; r++) mx[r] = -3.0e38f;
  #pragma unroll
  for (int kf = 0; kf < 25; kf++) {
    const int j = kf * 16 + c16;
    const bool kv = (kf < 24) ? (((kvm >> kf) & 1u) != 0) : (c16 == 0);
    #pragma unroll
    for (int r = 0; r < 4; r++) {
      const int c = cq + r;
      const bool keep = kv && (kf == 24 || (j >= c && j <= c + 256));
      const float val = keep ? s[kf][r] * 0.125f : -1.0e9f;
      s[kf][r] = val;
      mx[r] = fmaxf(mx[r], val);
    }
  }
  #pragma unroll
  for (int r = 0; r < 4; r++) {
    float m = mx[r];
    m = fmaxf(m, __shfl_xor(m, 1));
    m = fmaxf(m, __shfl_xor(m, 2));
    m = fmaxf(m, __shfl_xor(m, 4));
    m = fmaxf(m, __shfl_xor(m, 8));
    mx[r] = m;
    sm[r] = 0.f;
  }
  #pragma unroll
  for (int kf = 0; kf < 25; kf++)
    #pragma unroll
    for (int r = 0; r < 4; r++) {
      const float p = __expf(s[kf][r] - mx[r]);
      s[kf][r] = p;
      sm[r] += p;
    }
  float rinv[4];
  #pragma unroll
  for (int r = 0; r < 4; r++) {
    float t = sm[r];
    t += __shfl_xor(t, 1);
    t += __shfl_xor(t, 2);
    t += __shfl_xor(t, 4);
    t += __shfl_xor(t, 8);
    rinv[r] = 1.0f / t;
  }
  s[25] = (fx4){0.f, 0.f, 0.f, 0.f};

  u16* pb = Plds + (size_t)w * 16 * V_STR;
  #pragma unroll
  for (int kf = 0; kf < 26; kf++) {
    const int j = kf * 16 + c16;
    #pragma unroll
    for (int r = 0; r < 4; r++)
      pb[(g * 4 + r) * V_STR + j] = f2bf(s[kf][r]);
  }
  __syncthreads();

  fx4 o[4] = {};
  const u16* pr = Plds + (size_t)(w * 16 + c16) * V_STR + g * 8;
  #pragma unroll
  for (int kt = 0; kt < 13; kt++) {
    const bx8 pa = *(const bx8*)(pr + kt * 32);
    #pragma unroll
    for (int df = 0; df < 4; df++) {
      const bx8 vvf = *(const bx8*)&Vlds[(df * 16 + c16) * V_STR + kt * 32 + g * 8];
      o[df] = __builtin_amdgcn_mfma_f32_16x16x32_bf16(pa, vvf, o[df], 0, 0, 0);
    }
  }

  u16* ob = attnout + (size_t)b * L_SEQ * H_DIM + h * D_HEAD;
  const int posq = n * CHUNK + w * 16 + g * 4;
  #pragma unroll
  for (int df = 0; df < 4; df++)
    #pragma unroll
    for (int r = 0; r < 4; r++)
      ob[(size_t)(posq + r) * H_DIM + df * 16 + c16] = f2bf(o[df][r] * rinv[r]);
}

// ---------------- Global row (query position 0) ----------------
__global__ __launch_bounds__(256)
void attn_g_score(const u16* __restrict__ qkv, const int* __restrict__ amask,
                  float* __restrict__ sbuf, float* __restrict__ pmax)
{
  __shared__ float qs[D_HEAD];
  __shared__ float red[4];
  const int seg = blockIdx.x, bh = blockIdx.y;
  const int b = bh / N_HEADS, h = bh % N_HEADS;
  const u16* base = qkv + (size_t)b * L_SEQ * QKV_LD + h * D_HEAD;
  const int tid = threadIdx.x;

  if (tid < D_HEAD) qs[tid] = bf2f(base[tid]);
  __syncthreads();

  const int l = seg * 256 + tid;
  const ux8* kp = (const ux8*)(base + (size_t)l * QKV_LD + H_DIM);
  float dot = 0.f;
  #pragma unroll
  for (int i = 0; i < 8; i++) {
    const ux8 kv = kp[i];
    #pragma unroll
    for (int j = 0; j < 8; j++) dot += qs[i * 8 + j] * bf2f(kv[j]);
  }
  float sv = dot * 0.125f;
  if (amask[b * L_SEQ + l] == 0) sv = -1.0e9f;
  sbuf[(size_t)bh * L_SEQ + l] = sv;

  float m = sv;
  #pragma unroll
  for (int off = 32; off > 0; off >>= 1) m = fmaxf(m, __shfl_xor(m, off));
  if ((tid & 63) == 0) red[tid >> 6] = m;
  __syncthreads();
  if (tid == 0)
    pmax[bh * NSEG + seg] = fmaxf(fmaxf(red[0], red[1]), fmaxf(red[2], red[3]));
}

__global__ __launch_bounds__(256)
void attn_g_pv(const u16* __restrict__ qkv, const float* __restrict__ sbuf,
               const float* __restrict__ pmax, float* __restrict__ psum,
               float* __restrict__ po)
{
  __shared__ float es[256];
  __shared__ float red[4];
  const int seg = blockIdx.x, bh = blockIdx.y;
  const int b = bh / N_HEADS, h = bh % N_HEADS;
  const int tid = threadIdx.x;

  float M = -3.0e38f;
  #pragma unroll
  for (int i = 0; i < NSEG; i++) M = fmaxf(M, pmax[bh * NSEG + i]);

  const int l = seg * 256 + tid;
  const float e = __expf(sbuf[(size_t)bh * L_SEQ + l] - M);
  es[tid] = e;

  float t = e;
  #pragma unroll
  for (int off = 32; off > 0; off >>= 1) t += __shfl_xor(t, off);
  if ((tid & 63) == 0) red[tid >> 6] = t;
  __syncthreads();
  if (tid == 0) psum[bh * NSEG + seg] = red[0] + red[1] + red[2] + red[3];

  const int d = tid & 63, grp = tid >> 6;
  const u16* vb = qkv + (size_t)b * L_SEQ * QKV_LD + h * D_HEAD + 2 * H_DIM + d;
  float acc = 0.f;
  #pragma unroll 4
  for (int i = 0; i < 64; i++) {
    const int ll = seg * 256 + grp * 64 + i;
    acc += es[grp * 64 + i] * bf2f(vb[(size_t)ll * QKV_LD]);
  }
  po[(((size_t)bh * NSEG + seg) * 4 + grp) * D_HEAD + d] = acc;
}

__global__ __launch_bounds__(64)
void attn_g_combine(const float* __restrict__ psum, const float* __restrict__ po,
                    u16* __restrict__ attnout)
{
  const int bh = blockIdx.x;
  const int b = bh / N_HEADS, h = bh % N_HEADS;
  const int d = threadIdx.x;
  float S = 0.f;
  #pragma unroll
  for (int i = 0; i < NSEG; i++) S += psum[bh * NSEG + i];
  float acc = 0.f;
  #pragma unroll
  for (int i = 0; i < NSEG * 4; i++)
    acc += po[((size_t)bh * NSEG * 4 + i) * D_HEAD + d];
  attnout[(size_t)b * L_SEQ * H_DIM + h * D_HEAD + d] = f2bf(acc / S);
}

// ---------------- LayerNorm kernels (bf16 residual stream) ----------------
__device__ __forceinline__ void block_stats(float sum, float sq, float* red,
                                            float& mean, float& rstd)
{
  const int lane = threadIdx.x & 63, wv = threadIdx.x >> 6;
  #pragma unroll
  for (int off = 32; off > 0; off >>= 1) {
    sum += __shfl_xor(sum, off);
    sq  += __shfl_xor(sq, off);
  }
  if (lane == 0) { red[wv] = sum; red[4 + wv] = sq; }
  __syncthreads();
  sum = red[0] + red[1] + red[2] + red[3];
  sq  = red[4] + red[5] + red[6] + red[7];
  mean = sum * (1.0f / H_DIM);
  const float var = sq * (1.0f / H_DIM) - mean * mean;
  rstd = rsqrtf(var + EPS_LN);
}

__global__ __launch_bounds__(256)
void embed_ln_kernel(const int* __restrict__ ids, const float* __restrict__ wemb,
                     const float* __restrict__ pemb, const float* __restrict__ gam,
                     const float* __restrict__ bet, u16* __restrict__ xb)
{
  __shared__ float red[8];
  const int row = blockIdx.x, tid = threadIdx.x;
  const int l = row & (L_SEQ - 1);
  const int id = ids[row];
  float v[3]; float sum = 0.f, sq = 0.f;
  #pragma unroll
  for (int i = 0; i < 3; i++) {
    const int c = tid + i * 256;
    const float t = wemb[(size_t)id * H_DIM + c] + pemb[(size_t)l * H_DIM + c];
    v[i] = t; sum += t; sq += t * t;
  }
  float mean, rstd;
  block_stats(sum, sq, red, mean, rstd);
  #pragma unroll
  for (int i = 0; i < 3; i++) {
    const int c = tid + i * 256;
    const float y = (v[i] - mean) * rstd * gam[c] + bet[c];
    xb[(size_t)row * H_DIM + c] = f2bf(y);
  }
}

// x_new = LN(x_old + y), residual stream is post-LN x (bf16 == GEMM input)
__global__ __launch_bounds__(256)
void add_ln_kernel(u16* xio, const u16* __restrict__ yin,
                   const float* __restrict__ gam, const float* __restrict__ bet)
{
  __shared__ float red[8];
  const int row = blockIdx.x, tid = threadIdx.x;
  float v[3]; float sum = 0.f, sq = 0.f;
  #pragma unroll
  for (int i = 0; i < 3; i++) {
    const int c = tid + i * 256;
    const float t = bf2f(xio[(size_t)row * H_DIM + c]) + bf2f(yin[(size_t)row * H_DIM + c]);
    v[i] = t; sum += t; sq += t * t;
  }
  float mean, rstd;
  block_stats(sum, sq, red, mean, rstd);
  #pragma unroll
  for (int i = 0; i < 3; i++) {
    const int c = tid + i * 256;
    const float y = (v[i] - mean) * rstd * gam[c] + bet[c];
    xio[(size_t)row * H_DIM + c] = f2bf(y);
  }
}

// ---------------- Fused weight prep: all transposes + bias concats ----------------
// 13824 tile-blocks (2 layers x 6912) + 288 (wfc) + 18 (bias) = 14130 blocks.
__global__ __launch_bounds__(256)
void prep_weights(const float* __restrict__ Wq, const float* __restrict__ Wk,
                  const float* __restrict__ Wv, const float* __restrict__ Wo,
                  const float* __restrict__ W1, const float* __restrict__ W2,
                  const float* __restrict__ Wfc,
                  const float* __restrict__ bq, const float* __restrict__ bk,
                  const float* __restrict__ bv,
                  u16* __restrict__ wqkvT, u16* __restrict__ woT,
                  u16* __restrict__ w1T, u16* __restrict__ w2T,
                  u16* __restrict__ wfcT, float* __restrict__ bqkv)
{
  const int t = blockIdx.x;
  const int tid = threadIdx.x;
  if (t >= 14112) {   // bias concat: 18 blocks
    const int idx = t - 14112;
    const int l = idx / 9, j = idx % 9;
    const int i = j * 256 + tid;
    if (i < H_DIM)          bqkv[l * QKV_LD + i] = bq[l * H_DIM + i];
    else if (i < 2 * H_DIM) bqkv[l * QKV_LD + i] = bk[l * H_DIM + i - H_DIM];
    else if (i < 3 * H_DIM) bqkv[l * QKV_LD + i] = bv[l * H_DIM + i - 2 * H_DIM];
    return;
  }
  const float* src; u16* dst; int K, N, r;
  if (t < 13824) {
    const int l = t / 6912; r = t % 6912;
    if (r < 2304) {
      const int m = r / 576; r = r % 576; K = H_DIM; N = H_DIM;
      if (m == 0)      src = Wq + (size_t)l * H_DIM * H_DIM;
      else if (m == 1) src = Wk + (size_t)l * H_DIM * H_DIM;
      else if (m == 2) src = Wv + (size_t)l * H_DIM * H_DIM;
      else             src = Wo + (size_t)l * H_DIM * H_DIM;
      dst = (m < 3) ? wqkvT + (size_t)l * QKV_LD * H_DIM + (size_t)m * H_DIM * H_DIM
                    : woT + (size_t)l * H_DIM * H_DIM;
    } else if (r < 4608) {
      r -= 2304; K = H_DIM; N = FF_DIM;
      src = W1 + (size_t)l * H_DIM * FF_DIM;
      dst = w1T + (size_t)l * FF_DIM * H_DIM;
    } else {
      r -= 4608; K = FF_DIM; N = H_DIM;
      src = W2 + (size_t)l * FF_DIM * H_DIM;
      dst = w2T + (size_t)l * H_DIM * FF_DIM;
    }
  } else {
    r = t - 13824; K = H_DIM; N = OUT_DIM; src = Wfc; dst = wfcT;
  }
  const int ntn = N >> 5;
  const int k0 = (r / ntn) * 32, n0 = (r % ntn) * 32;
  __shared__ float tile[32][33];
  const int tx = tid & 31, ty = tid >> 5;
  #pragma unroll
  for (int i = 0; i < 32; i += 8)
    tile[ty + i][tx] = src[(size_t)(k0 + ty + i) * N + n0 + tx];
  __syncthreads();
  #pragma unroll
  for (int i = 0; i < 32; i += 8)
    dst[(size_t)(n0 + ty + i) * K + k0 + tx] = f2bf(tile[tx][ty + i]);
}

// ---------------- host ----------------
extern "C" void kernel_launch(void* const* d_in, const int* in_sizes, int n_in,
                              void* d_out, int out_size, void* d_ws, size_t ws_size,
                              hipStream_t stream)
{
  (void)in_sizes; (void)n_in; (void)out_size; (void)ws_size;
  const int*   ids   = (const int*)d_in[0];
  const int*   amask = (const int*)d_in[1];
  const float* wemb  = (const float*)d_in[2];
  const float* pemb  = (const float*)d_in[3];
  const float* elns  = (const float*)d_in[4];
  const float* elnb  = (const float*)d_in[5];
  const float* Wq    = (const float*)d_in[6];
  const float* bq    = (const float*)d_in[7];
  const float* Wk    = (const float*)d_in[8];
  const float* bk    = (const float*)d_in[9];
  const float* Wv    = (const float*)d_in[10];
  const float* bv    = (const float*)d_in[11];
  const float* Wo    = (const float*)d_in[12];
  const float* bo    = (const float*)d_in[13];
  const float* ln1s  = (const float*)d_in[14];
  const float* ln1b  = (const float*)d_in[15];
  const float* W1    = (const float*)d_in[16];
  const float* b1    = (const float*)d_in[17];
  const float* W2    = (const float*)d_in[18];
  const float* b2    = (const float*)d_in[19];
  const float* ln2s  = (const float*)d_in[20];
  const float* ln2b  = (const float*)d_in[21];
  const float* Wfc   = (const float*)d_in[22];
  const float* bfc   = (const float*)d_in[23];

  char* ws = (char*)d_ws;
  size_t off = 0;
  auto alloc = [&](size_t bytes) -> void* {
    void* p = ws + off;
    off += (bytes + 255) & ~(size_t)255;
    return p;
  };
  u16* xb     = (u16*)alloc((size_t)M_ROWS * H_DIM * 2);   // residual stream (post-LN)
  u16* projb  = (u16*)alloc((size_t)M_ROWS * H_DIM * 2);
  u16* big    = (u16*)alloc((size_t)M_ROWS * FF_DIM * 2);  // qkv / ff1 time-share
  u16* attno  = (u16*)alloc((size_t)M_ROWS * H_DIM * 2);
  u16* wqkvT  = (u16*)alloc((size_t)2 * QKV_LD * H_DIM * 2);
  u16* woT    = (u16*)alloc((size_t)2 * H_DIM * H_DIM * 2);
  u16* w1T    = (u16*)alloc((size_t)2 * FF_DIM * H_DIM * 2);
  u16* w2T    = (u16*)alloc((size_t)2 * H_DIM * FF_DIM * 2);
  u16* wfcT   = (u16*)alloc((size_t)OUT_DIM * H_DIM * 2);
  float* bqkv = (float*)alloc(2 * QKV_LD * 4);
  float* gsc  = (float*)alloc((size_t)BATCH * N_HEADS * L_SEQ * 4);
  float* gpm  = (float*)alloc((size_t)BATCH * N_HEADS * NSEG * 4);
  float* gps  = (float*)alloc((size_t)BATCH * N_HEADS * NSEG * 4);
  float* gpo  = (float*)alloc((size_t)BATCH * N_HEADS * NSEG * 4 * D_HEAD * 4);

  u16* qkvb = big;
  u16* ff1  = big;

  prep_weights<<<14130, 256, 0, stream>>>(Wq, Wk, Wv, Wo, W1, W2, Wfc,
                                          bq, bk, bv,
                                          wqkvT, woT, w1T, w2T, wfcT, bqkv);
  embed_ln_kernel<<<M_ROWS, 256, 0, stream>>>(ids, wemb, pemb, elns, elnb, xb);

  for (int l = 0; l < 2; l++) {
    gemm_s<1, 0, 0><<<(M_ROWS / 128) * (QKV_LD / 128), 256, 0, stream>>>(
        xb, wqkvT + (size_t)l * QKV_LD * H_DIM, bqkv + l * QKV_LD,
        nullptr, qkvb, nullptr, QKV_LD, H_DIM);
    attn_local_kernel<<<BATCH * N_HEADS * N_CHUNK, 512, 0, stream>>>(qkvb, amask, attno);
    attn_g_score<<<dim3(NSEG, BATCH * N_HEADS), 256, 0, stream>>>(qkvb, amask, gsc, gpm);
    attn_g_pv<<<dim3(NSEG, BATCH * N_HEADS), 256, 0, stream>>>(qkvb, gsc, gpm, gps, gpo);
    attn_g_combine<<<BATCH * N_HEADS, 64, 0, stream>>>(gps, gpo, attno);
    gemm_s<1, 0, 0><<<(M_ROWS / 128) * (H_DIM / 128), 256, 0, stream>>>(
        attno, woT + (size_t)l * H_DIM * H_DIM, bo + l * H_DIM,
        nullptr, projb, nullptr, H_DIM, H_DIM);
    add_ln_kernel<<<M_ROWS, 256, 0, stream>>>(xb, projb, ln1s + l * H_DIM, ln1b + l * H_DIM);
    gemm_s<1, 1, 0><<<(M_ROWS / 128) * (FF_DIM / 128), 256, 0, stream>>>(
        xb, w1T + (size_t)l * FF_DIM * H_DIM, b1 + l * FF_DIM,
        nullptr, ff1, nullptr, FF_DIM, H_DIM);
    gemm_s<1, 0, 0><<<(M_ROWS / 128) * (H_DIM / 128), 256, 0, stream>>>(
        ff1, w2T + (size_t)l * H_DIM * FF_DIM, b2 + l * H_DIM,
        nullptr, projb, nullptr, H_DIM, FF_DIM);
    add_ln_kernel<<<M_ROWS, 256, 0, stream>>>(xb, projb, ln2s + l * H_DIM, ln2b + l * H_DIM);
  }

  float* vdn = (float*)d_out;
  float* cls = vdn + (size_t)BATCH * L_SEQ * OUT_DIM;
  gemm_s<0, 0, 1><<<(M_ROWS / 128) * (OUT_DIM / 128), 256, 0, stream>>>(
      xb, wfcT, bfc, vdn, nullptr, cls, OUT_DIM, H_DIM);
}